// Round 19
// baseline (6070.240 us; speedup 1.0000x reference)
//
#include <hip/hip_runtime.h>

// ============================================================================
// ROUND 19: occupancy axis. 64 KiB LDS (granule-level double buffer, 32-k
// steps) -> 2 blocks/CU, 16 waves/CU, so barrier/drain dead time of one block
// is filled by the other (m114 mechanism). Per step:
//   12 ds_read ; lgkmcnt(0) ; BAR ; stage g(s+2)->freed buf (4 loads) ;
//   32 MFMA ; vmcnt(4) ; BAR
// Operand geometry, XOR swizzle (0 conflicts), fragments, epilogue, converts
// identical to r18 (best: GEMM 517 us / MfmaUtil 48.6).
// ============================================================================

#define H     4096
#define NROWS 16384
#define NEXP  4
#define NSTEP 128         // 32-k granule steps

typedef __attribute__((ext_vector_type(8))) __bf16 bf16x8;
typedef __attribute__((ext_vector_type(4))) float  f32x4;

#define BAR()     asm volatile("s_barrier" ::: "memory")
#define VMCNT0()  asm volatile("s_waitcnt vmcnt(0)" ::: "memory")
#define VMCNT4()  asm volatile("s_waitcnt vmcnt(4)" ::: "memory")
#define LGKMCNT0() asm volatile("s_waitcnt lgkmcnt(0)" ::: "memory")

__device__ __forceinline__ void gload16(const char* g, char* l) {
    __builtin_amdgcn_global_load_lds(
        (const __attribute__((address_space(1))) void*)g,
        (__attribute__((address_space(3))) void*)l, 16, 0, 0);
}

// ---------------------------------------------------------------------------
// Convert kernels (memory-bound; at HBM roofline, ~121 us total).
// ---------------------------------------------------------------------------
__global__ __launch_bounds__(256) void norm_convert(
    const float* __restrict__ x, const float* __restrict__ nw,
    __bf16* __restrict__ out) {
    const size_t nthread8 = (size_t)NROWS * H / 8;
    for (size_t i = (size_t)blockIdx.x * 256 + threadIdx.x; i < nthread8;
         i += (size_t)gridDim.x * 256) {
        const size_t base = i * 8;
        const int e = (int)(base >> 24);
        const int k = (int)(base & (size_t)(H - 1));
        const float4 v0 = *(const float4*)(x + base);
        const float4 v1 = *(const float4*)(x + base + 4);
        const float4 w0 = *(const float4*)(nw + (size_t)e * H + k);
        const float4 w1 = *(const float4*)(nw + (size_t)e * H + k + 4);
        bf16x8 r;
        r[0] = (__bf16)(v0.x * (w0.x + 1.0f));
        r[1] = (__bf16)(v0.y * (w0.y + 1.0f));
        r[2] = (__bf16)(v0.z * (w0.z + 1.0f));
        r[3] = (__bf16)(v0.w * (w0.w + 1.0f));
        r[4] = (__bf16)(v1.x * (w1.x + 1.0f));
        r[5] = (__bf16)(v1.y * (w1.y + 1.0f));
        r[6] = (__bf16)(v1.z * (w1.z + 1.0f));
        r[7] = (__bf16)(v1.w * (w1.w + 1.0f));
        *(bf16x8*)(out + base) = r;
    }
}

__global__ __launch_bounds__(256) void w_convert(
    const float* __restrict__ wf, __bf16* __restrict__ out) {
    const size_t nthread8 = (size_t)NEXP * H * H / 8;
    for (size_t i = (size_t)blockIdx.x * 256 + threadIdx.x; i < nthread8;
         i += (size_t)gridDim.x * 256) {
        const size_t base = i * 8;
        const float4 v0 = *(const float4*)(wf + base);
        const float4 v1 = *(const float4*)(wf + base + 4);
        bf16x8 r;
        r[0] = (__bf16)v0.x; r[1] = (__bf16)v0.y;
        r[2] = (__bf16)v0.z; r[3] = (__bf16)v0.w;
        r[4] = (__bf16)v1.x; r[5] = (__bf16)v1.y;
        r[6] = (__bf16)v1.z; r[7] = (__bf16)v1.w;
        *(bf16x8*)(out + base) = r;
    }
}

// ---------------------------------------------------------------------------
// Granule-dbuf 256^2 GEMM, 64 KiB LDS, 2 blocks/CU.
// 512 threads = 8 waves (2Mx4N), per-wave 128x64 output (acc[8][4]).
// ---------------------------------------------------------------------------
__global__ __launch_bounds__(512, 4) void gemm_bf16_gdb(
    const __bf16* __restrict__ A,    // (NROWS, H) bf16
    const __bf16* __restrict__ Wb,   // (NEXP, H, H) bf16
    float* __restrict__ C) {         // (NROWS, H) fp32
    // buf b at b*32768: A granule at +0, B granule at +16384 (each 256x32 bf16)
    __shared__ __align__(16) char lds[65536];

    const int tid  = threadIdx.x;
    const int lane = tid & 63;
    const int w    = tid >> 6;    // 0..7
    const int wr   = w >> 2;      // 0..1: rows wr*128..+127
    const int wc   = w & 3;       // 0..3: cols wc*64..+63

    // T1: bijective XCD swizzle (1024 blocks, 1024%8==0).
    const int bid = blockIdx.x;
    const int swz = (bid & 7) * 128 + (bid >> 3);
    const int bx  = swz & 15;
    const int by  = swz >> 4;
    const int e   = by >> 4;
    const int row0 = by * 256;
    const int col0 = bx * 256;

    const char* Ab = (const char*)A;
    const char* Bb = (const char*)(Wb + (size_t)e * H * H);

    // Staging (r18 exact geometry): thread stages row srow (+128 on 2nd
    // gload), 16B at inverse-swizzled source slot; LDS dest linear.
    const int    srow  = tid >> 2;
    const int    sslot = (((tid & 3) ^ ((tid >> 3) & 3)) << 4);
    const size_t a_g0  = ((size_t)(row0 + srow) * H) * 2 + sslot;
    const size_t a_g1  = a_g0 + (size_t)128 * H * 2;
    const size_t b_g0  = ((size_t)(col0 + srow) * H) * 2 + sslot;
    const size_t b_g1  = b_g0 + (size_t)128 * H * 2;
    const int    lds_t = tid * 16;

    // Read constants (r18 exact): phys slot = slog ^ ((l15>>1)&3).
    const int l15   = lane & 15;
    const int slog  = lane >> 4;
    const int pslot = ((slog ^ ((l15 >> 1) & 3)) << 4);

    f32x4 acc[8][4] = {};

#define STAGE(base, koff, g0, g1, ldst)                       \
    do {                                                      \
        gload16(base + g0 + (koff), (ldst) + lds_t);          \
        gload16(base + g1 + (koff), (ldst) + 8192 + lds_t);   \
    } while (0)
#define LDF(dst, gran, rowe) \
    dst = *(const bf16x8*)((gran) + (rowe) * 64 + pslot)

    // ---- prologue: stage g0 -> buf0, g1 -> buf1; drain g0 only ----
    {
        STAGE(Ab, 0,  a_g0, a_g1, lds);
        STAGE(Bb, 0,  b_g0, b_g1, lds + 16384);
        STAGE(Ab, 64, a_g0, a_g1, lds + 32768);
        STAGE(Bb, 64, b_g0, b_g1, lds + 49152);
        VMCNT4();          // g0 resident; g1 stays in flight
        BAR();
    }

    // ---- main loop: one 32-k granule per step ----
#define STEPBODY(s)                                                          \
    do {                                                                     \
        char* bA = lds + ((s) & 1) * 32768;                                  \
        char* bB = bA + 16384;                                               \
        bf16x8 a[8], b[4];                                                   \
        _Pragma("unroll")                                                    \
        for (int n = 0; n < 4; ++n) LDF(b[n], bB, wc * 64 + n * 16 + l15);   \
        _Pragma("unroll")                                                    \
        for (int m = 0; m < 8; ++m) LDF(a[m], bA, wr * 128 + m * 16 + l15);  \
        LGKMCNT0();                                                          \
        BAR();             /* buf(s&1) reads done -> safe to overwrite */    \
        if ((s) + 2 < NSTEP) {                                               \
            const size_t kn = (size_t)((s) + 2) * 64;                        \
            STAGE(Ab, kn, a_g0, a_g1, bA);                                   \
            STAGE(Bb, kn, b_g0, b_g1, bB);                                   \
        }                                                                    \
        __builtin_amdgcn_s_setprio(1);                                       \
        _Pragma("unroll")                                                    \
        for (int m = 0; m < 8; ++m)                                          \
            _Pragma("unroll")                                                \
            for (int n = 0; n < 4; ++n)                                      \
                acc[m][n] = __builtin_amdgcn_mfma_f32_16x16x32_bf16(         \
                    a[m], b[n], acc[m][n], 0, 0, 0);                         \
        __builtin_amdgcn_s_setprio(0);                                       \
        if ((s) + 2 < NSTEP)      VMCNT4();  /* drains g(s+1) */             \
        else if ((s) + 1 < NSTEP) VMCNT0();  /* edge: drain final granule */ \
        BAR();             /* g(s+1) visible to all waves */                 \
    } while (0)

    for (int s2 = 0; s2 < NSTEP; s2 += 2) {
        STEPBODY(s2);
        STEPBODY(s2 + 1);
    }
#undef STEPBODY

    // Epilogue: C/D layout col = lane&15, row = (lane>>4)*4 + j  [m89].
    const int fq = slog * 4;
    #pragma unroll
    for (int m8 = 0; m8 < 8; ++m8) {
        #pragma unroll
        for (int n = 0; n < 4; ++n) {
            #pragma unroll
            for (int j = 0; j < 4; ++j) {
                const int gr = row0 + wr * 128 + m8 * 16 + fq + j;
                const int gc = col0 + wc * 64 + n * 16 + l15;
                C[(size_t)gr * H + gc] = acc[m8][n][j];
            }
        }
    }
#undef STAGE
#undef LDF
}

// ---------------------------------------------------------------------------
// FALLBACK (ws too small): round-12 fused kernel (verified passing, 430 TF).
// ---------------------------------------------------------------------------
#define BM 128
#define BN 128
#define BK 64
__global__ __launch_bounds__(256, 2) void fused_norm_gemm_f32w(
    const float* __restrict__ X, const float* __restrict__ NW,
    const float* __restrict__ Wf, float* __restrict__ C) {
    __shared__ __align__(16) __bf16 As[BM * BK];
    __shared__ __align__(16) __bf16 Bs[BN * BK];
    const int tid = threadIdx.x, lane = tid & 63, w = tid >> 6;
    const int wr = w >> 1, wc = w & 1;
    const int row0 = blockIdx.y * BM, col0 = blockIdx.x * BN;
    f32x4 acc[4][4] = {};
    const int a_kc = (tid & 7) * 8, a_r0 = tid >> 3;
    char* AsB = (char*)As; char* BsB = (char*)Bs;
    for (int kt = 0; kt < H; kt += BK) {
        __syncthreads();
        float4 xv[4][2], bv[4][2];
        #pragma unroll
        for (int it = 0; it < 4; ++it) {
            const float* xp = X + (size_t)(row0 + it * 32 + a_r0) * H + kt + a_kc;
            xv[it][0] = *(const float4*)xp; xv[it][1] = *(const float4*)(xp + 4);
        }
        #pragma unroll
        for (int it = 0; it < 4; ++it) {
            const float* bp = Wf + (size_t)(col0 + it * 32 + a_r0) * H + kt + a_kc;
            bv[it][0] = *(const float4*)bp; bv[it][1] = *(const float4*)(bp + 4);
        }
        float4 w0 = *(const float4*)(NW + kt + a_kc);
        float4 w1 = *(const float4*)(NW + kt + a_kc + 4);
        w0.x += 1.0f; w0.y += 1.0f; w0.z += 1.0f; w0.w += 1.0f;
        w1.x += 1.0f; w1.y += 1.0f; w1.z += 1.0f; w1.w += 1.0f;
        #pragma unroll
        for (int it = 0; it < 4; ++it) {
            bf16x8 r;
            r[0] = (__bf16)(xv[it][0].x * w0.x); r[1] = (__bf16)(xv[it][0].y * w0.y);
            r[2] = (__bf16)(xv[it][0].z * w0.z); r[3] = (__bf16)(xv[it][0].w * w0.w);
            r[4] = (__bf16)(xv[it][1].x * w1.x); r[5] = (__bf16)(xv[it][1].y * w1.y);
            r[6] = (__bf16)(xv[it][1].z * w1.z); r[7] = (__bf16)(xv[it][1].w * w1.w);
            *(bf16x8*)(AsB + (it * 32 + a_r0) * 128 + a_kc * 2) = r;
        }
        #pragma unroll
        for (int it = 0; it < 4; ++it) {
            bf16x8 r;
            r[0] = (__bf16)bv[it][0].x; r[1] = (__bf16)bv[it][0].y;
            r[2] = (__bf16)bv[it][0].z; r[3] = (__bf16)bv[it][0].w;
            r[4] = (__bf16)bv[it][1].x; r[5] = (__bf16)bv[it][1].y;
            r[6] = (__bf16)bv[it][1].z; r[7] = (__bf16)bv[it][1].w;
            *(bf16x8*)(BsB + (it * 32 + a_r0) * 128 + a_kc * 2) = r;
        }
        __syncthreads();
        #pragma unroll
        for (int kh = 0; kh < 2; ++kh) {
            const int kb = kh * 4 + (lane >> 4);
            bf16x8 af[4], bfr[4];
            #pragma unroll
            for (int m = 0; m < 4; ++m) {
                const int r = wr * 64 + m * 16 + (lane & 15);
                af[m] = *(const bf16x8*)(AsB + r * 128 + kb * 16);
            }
            #pragma unroll
            for (int n = 0; n < 4; ++n) {
                const int r = wc * 64 + n * 16 + (lane & 15);
                bfr[n] = *(const bf16x8*)(BsB + r * 128 + kb * 16);
            }
            #pragma unroll
            for (int m = 0; m < 4; ++m)
                #pragma unroll
                for (int n = 0; n < 4; ++n)
                    acc[m][n] = __builtin_amdgcn_mfma_f32_16x16x32_bf16(
                        af[m], bfr[n], acc[m][n], 0, 0, 0);
        }
    }
    const int fr = lane & 15, fq = (lane >> 4) * 4;
    #pragma unroll
    for (int m = 0; m < 4; ++m)
        #pragma unroll
        for (int n = 0; n < 4; ++n)
            #pragma unroll
            for (int j = 0; j < 4; ++j) {
                const int gr = row0 + wr * 64 + m * 16 + fq + j;
                const int gc = col0 + wc * 64 + n * 16 + fr;
                C[(size_t)gr * H + gc] = acc[m][n][j];
            }
}

// ---------------------------------------------------------------------------
// Host. d_in[2] is FP32 (npz upcast). ws: [0,134MB)=normed-x bf16,
// [134MB,268MB)=W bf16. Fallback if ws too small.
// ---------------------------------------------------------------------------
extern "C" void kernel_launch(void* const* d_in, const int* in_sizes, int n_in,
                              void* d_out, int out_size, void* d_ws, size_t ws_size,
                              hipStream_t stream) {
    (void)in_sizes; (void)n_in; (void)out_size;
    const float* x  = (const float*)d_in[0];
    const float* nw = (const float*)d_in[1];
    const float* wf = (const float*)d_in[2];
    float* out = (float*)d_out;

    const size_t xe_bytes = (size_t)NROWS * H * 2;
    const size_t we_bytes = (size_t)NEXP * H * H * 2;

    if (ws_size >= xe_bytes + we_bytes) {
        __bf16* ws_x = (__bf16*)d_ws;
        __bf16* ws_w = (__bf16*)((char*)d_ws + xe_bytes);
        norm_convert<<<2048, 256, 0, stream>>>(x, nw, ws_x);
        w_convert<<<2048, 256, 0, stream>>>(wf, ws_w);
        gemm_bf16_gdb<<<1024, 512, 0, stream>>>(ws_x, ws_w, out);
    } else {
        dim3 grid(H / BN, 4096 / BM);
        for (int i = 0; i < NEXP; ++i) {
            fused_norm_gemm_f32w<<<grid, 256, 0, stream>>>(
                x + (size_t)i * 4096 * H, nw + (size_t)i * H,
                wf + (size_t)i * H * H, out + (size_t)i * 4096 * H);
        }
    }
}

// Round 20
// 664.014 us; speedup vs baseline: 9.1417x; 9.1417x over previous
//
#include <hip/hip_runtime.h>

// ============================================================================
// ROUND 20: r19's 64-KiB granule-dbuf kernel with the spill confound removed:
// __launch_bounds__(512, 2) instead of (512, 4). r19's 6.1ms was VGPR=64
// register spill (30 GB scratch traffic), NOT the schedule. With (512,2) the
// allocator lands ~96-110 VGPR (r17 precedent: 96 for the same body); actual
// VGPR <= 128 + LDS 64 KiB => hardware can still co-residence 2 blocks/CU.
// Per step: 12 ds_read ; lgkmcnt(0) ; BAR ; stage g(s+2)->freed buf ;
// 32 MFMA ; vmcnt(4) ; BAR.  Swizzle/fragments/epilogue/converts = r18.
// ============================================================================

#define H     4096
#define NROWS 16384
#define NEXP  4
#define NSTEP 128         // 32-k granule steps

typedef __attribute__((ext_vector_type(8))) __bf16 bf16x8;
typedef __attribute__((ext_vector_type(4))) float  f32x4;

#define BAR()     asm volatile("s_barrier" ::: "memory")
#define VMCNT0()  asm volatile("s_waitcnt vmcnt(0)" ::: "memory")
#define VMCNT4()  asm volatile("s_waitcnt vmcnt(4)" ::: "memory")
#define LGKMCNT0() asm volatile("s_waitcnt lgkmcnt(0)" ::: "memory")

__device__ __forceinline__ void gload16(const char* g, char* l) {
    __builtin_amdgcn_global_load_lds(
        (const __attribute__((address_space(1))) void*)g,
        (__attribute__((address_space(3))) void*)l, 16, 0, 0);
}

// ---------------------------------------------------------------------------
// Convert kernels (memory-bound; at HBM roofline, ~121 us total).
// ---------------------------------------------------------------------------
__global__ __launch_bounds__(256) void norm_convert(
    const float* __restrict__ x, const float* __restrict__ nw,
    __bf16* __restrict__ out) {
    const size_t nthread8 = (size_t)NROWS * H / 8;
    for (size_t i = (size_t)blockIdx.x * 256 + threadIdx.x; i < nthread8;
         i += (size_t)gridDim.x * 256) {
        const size_t base = i * 8;
        const int e = (int)(base >> 24);
        const int k = (int)(base & (size_t)(H - 1));
        const float4 v0 = *(const float4*)(x + base);
        const float4 v1 = *(const float4*)(x + base + 4);
        const float4 w0 = *(const float4*)(nw + (size_t)e * H + k);
        const float4 w1 = *(const float4*)(nw + (size_t)e * H + k + 4);
        bf16x8 r;
        r[0] = (__bf16)(v0.x * (w0.x + 1.0f));
        r[1] = (__bf16)(v0.y * (w0.y + 1.0f));
        r[2] = (__bf16)(v0.z * (w0.z + 1.0f));
        r[3] = (__bf16)(v0.w * (w0.w + 1.0f));
        r[4] = (__bf16)(v1.x * (w1.x + 1.0f));
        r[5] = (__bf16)(v1.y * (w1.y + 1.0f));
        r[6] = (__bf16)(v1.z * (w1.z + 1.0f));
        r[7] = (__bf16)(v1.w * (w1.w + 1.0f));
        *(bf16x8*)(out + base) = r;
    }
}

__global__ __launch_bounds__(256) void w_convert(
    const float* __restrict__ wf, __bf16* __restrict__ out) {
    const size_t nthread8 = (size_t)NEXP * H * H / 8;
    for (size_t i = (size_t)blockIdx.x * 256 + threadIdx.x; i < nthread8;
         i += (size_t)gridDim.x * 256) {
        const size_t base = i * 8;
        const float4 v0 = *(const float4*)(wf + base);
        const float4 v1 = *(const float4*)(wf + base + 4);
        bf16x8 r;
        r[0] = (__bf16)v0.x; r[1] = (__bf16)v0.y;
        r[2] = (__bf16)v0.z; r[3] = (__bf16)v0.w;
        r[4] = (__bf16)v1.x; r[5] = (__bf16)v1.y;
        r[6] = (__bf16)v1.z; r[7] = (__bf16)v1.w;
        *(bf16x8*)(out + base) = r;
    }
}

// ---------------------------------------------------------------------------
// Granule-dbuf 256^2 GEMM, 64 KiB LDS; launch_bounds(512,2) -> no VGPR cap,
// 2 blocks/CU if VGPR <= 128 (expected ~96-110).
// ---------------------------------------------------------------------------
__global__ __launch_bounds__(512, 2) void gemm_bf16_gdb(
    const __bf16* __restrict__ A,    // (NROWS, H) bf16
    const __bf16* __restrict__ Wb,   // (NEXP, H, H) bf16
    float* __restrict__ C) {         // (NROWS, H) fp32
    // buf b at b*32768: A granule at +0, B granule at +16384 (each 256x32 bf16)
    __shared__ __align__(16) char lds[65536];

    const int tid  = threadIdx.x;
    const int lane = tid & 63;
    const int w    = tid >> 6;    // 0..7
    const int wr   = w >> 2;      // 0..1: rows wr*128..+127
    const int wc   = w & 3;       // 0..3: cols wc*64..+63

    // T1: bijective XCD swizzle (1024 blocks, 1024%8==0).
    const int bid = blockIdx.x;
    const int swz = (bid & 7) * 128 + (bid >> 3);
    const int bx  = swz & 15;
    const int by  = swz >> 4;
    const int e   = by >> 4;
    const int row0 = by * 256;
    const int col0 = bx * 256;

    const char* Ab = (const char*)A;
    const char* Bb = (const char*)(Wb + (size_t)e * H * H);

    const int    srow  = tid >> 2;
    const int    sslot = (((tid & 3) ^ ((tid >> 3) & 3)) << 4);
    const size_t a_g0  = ((size_t)(row0 + srow) * H) * 2 + sslot;
    const size_t a_g1  = a_g0 + (size_t)128 * H * 2;
    const size_t b_g0  = ((size_t)(col0 + srow) * H) * 2 + sslot;
    const size_t b_g1  = b_g0 + (size_t)128 * H * 2;
    const int    lds_t = tid * 16;

    const int l15   = lane & 15;
    const int slog  = lane >> 4;
    const int pslot = ((slog ^ ((l15 >> 1) & 3)) << 4);

    f32x4 acc[8][4] = {};

#define STAGE(base, koff, g0, g1, ldst)                       \
    do {                                                      \
        gload16(base + g0 + (koff), (ldst) + lds_t);          \
        gload16(base + g1 + (koff), (ldst) + 8192 + lds_t);   \
    } while (0)
#define LDF(dst, gran, rowe) \
    dst = *(const bf16x8*)((gran) + (rowe) * 64 + pslot)

    // ---- prologue: stage g0 -> buf0, g1 -> buf1; drain g0 only ----
    {
        STAGE(Ab, 0,  a_g0, a_g1, lds);
        STAGE(Bb, 0,  b_g0, b_g1, lds + 16384);
        STAGE(Ab, 64, a_g0, a_g1, lds + 32768);
        STAGE(Bb, 64, b_g0, b_g1, lds + 49152);
        VMCNT4();          // g0 resident; g1 stays in flight
        BAR();
    }

    // ---- main loop: one 32-k granule per step ----
#define STEPBODY(s)                                                          \
    do {                                                                     \
        char* bA = lds + ((s) & 1) * 32768;                                  \
        char* bB = bA + 16384;                                               \
        bf16x8 a[8], b[4];                                                   \
        _Pragma("unroll")                                                    \
        for (int n = 0; n < 4; ++n) LDF(b[n], bB, wc * 64 + n * 16 + l15);   \
        _Pragma("unroll")                                                    \
        for (int m = 0; m < 8; ++m) LDF(a[m], bA, wr * 128 + m * 16 + l15);  \
        LGKMCNT0();                                                          \
        BAR();             /* buf(s&1) reads done -> safe to overwrite */    \
        if ((s) + 2 < NSTEP) {                                               \
            const size_t kn = (size_t)((s) + 2) * 64;                        \
            STAGE(Ab, kn, a_g0, a_g1, bA);                                   \
            STAGE(Bb, kn, b_g0, b_g1, bB);                                   \
        }                                                                    \
        __builtin_amdgcn_s_setprio(1);                                       \
        _Pragma("unroll")                                                    \
        for (int m = 0; m < 8; ++m)                                          \
            _Pragma("unroll")                                                \
            for (int n = 0; n < 4; ++n)                                      \
                acc[m][n] = __builtin_amdgcn_mfma_f32_16x16x32_bf16(         \
                    a[m], b[n], acc[m][n], 0, 0, 0);                         \
        __builtin_amdgcn_s_setprio(0);                                       \
        if ((s) + 2 < NSTEP)      VMCNT4();  /* drains g(s+1) */             \
        else if ((s) + 1 < NSTEP) VMCNT0();  /* edge: drain final granule */ \
        BAR();             /* g(s+1) visible to all waves */                 \
    } while (0)

    for (int s2 = 0; s2 < NSTEP; s2 += 2) {
        STEPBODY(s2);
        STEPBODY(s2 + 1);
    }
#undef STEPBODY

    // Epilogue: C/D layout col = lane&15, row = (lane>>4)*4 + j  [m89].
    const int fq = slog * 4;
    #pragma unroll
    for (int m8 = 0; m8 < 8; ++m8) {
        #pragma unroll
        for (int n = 0; n < 4; ++n) {
            #pragma unroll
            for (int j = 0; j < 4; ++j) {
                const int gr = row0 + wr * 128 + m8 * 16 + fq + j;
                const int gc = col0 + wc * 64 + n * 16 + l15;
                C[(size_t)gr * H + gc] = acc[m8][n][j];
            }
        }
    }
#undef STAGE
#undef LDF
}

// ---------------------------------------------------------------------------
// FALLBACK (ws too small): round-12 fused kernel (verified passing, 430 TF).
// ---------------------------------------------------------------------------
#define BM 128
#define BN 128
#define BK 64
__global__ __launch_bounds__(256, 2) void fused_norm_gemm_f32w(
    const float* __restrict__ X, const float* __restrict__ NW,
    const float* __restrict__ Wf, float* __restrict__ C) {
    __shared__ __align__(16) __bf16 As[BM * BK];
    __shared__ __align__(16) __bf16 Bs[BN * BK];
    const int tid = threadIdx.x, lane = tid & 63, w = tid >> 6;
    const int wr = w >> 1, wc = w & 1;
    const int row0 = blockIdx.y * BM, col0 = blockIdx.x * BN;
    f32x4 acc[4][4] = {};
    const int a_kc = (tid & 7) * 8, a_r0 = tid >> 3;
    char* AsB = (char*)As; char* BsB = (char*)Bs;
    for (int kt = 0; kt < H; kt += BK) {
        __syncthreads();
        float4 xv[4][2], bv[4][2];
        #pragma unroll
        for (int it = 0; it < 4; ++it) {
            const float* xp = X + (size_t)(row0 + it * 32 + a_r0) * H + kt + a_kc;
            xv[it][0] = *(const float4*)xp; xv[it][1] = *(const float4*)(xp + 4);
        }
        #pragma unroll
        for (int it = 0; it < 4; ++it) {
            const float* bp = Wf + (size_t)(col0 + it * 32 + a_r0) * H + kt + a_kc;
            bv[it][0] = *(const float4*)bp; bv[it][1] = *(const float4*)(bp + 4);
        }
        float4 w0 = *(const float4*)(NW + kt + a_kc);
        float4 w1 = *(const float4*)(NW + kt + a_kc + 4);
        w0.x += 1.0f; w0.y += 1.0f; w0.z += 1.0f; w0.w += 1.0f;
        w1.x += 1.0f; w1.y += 1.0f; w1.z += 1.0f; w1.w += 1.0f;
        #pragma unroll
        for (int it = 0; it < 4; ++it) {
            bf16x8 r;
            r[0] = (__bf16)(xv[it][0].x * w0.x); r[1] = (__bf16)(xv[it][0].y * w0.y);
            r[2] = (__bf16)(xv[it][0].z * w0.z); r[3] = (__bf16)(xv[it][0].w * w0.w);
            r[4] = (__bf16)(xv[it][1].x * w1.x); r[5] = (__bf16)(xv[it][1].y * w1.y);
            r[6] = (__bf16)(xv[it][1].z * w1.z); r[7] = (__bf16)(xv[it][1].w * w1.w);
            *(bf16x8*)(AsB + (it * 32 + a_r0) * 128 + a_kc * 2) = r;
        }
        #pragma unroll
        for (int it = 0; it < 4; ++it) {
            bf16x8 r;
            r[0] = (__bf16)bv[it][0].x; r[1] = (__bf16)bv[it][0].y;
            r[2] = (__bf16)bv[it][0].z; r[3] = (__bf16)bv[it][0].w;
            r[4] = (__bf16)bv[it][1].x; r[5] = (__bf16)bv[it][1].y;
            r[6] = (__bf16)bv[it][1].z; r[7] = (__bf16)bv[it][1].w;
            *(bf16x8*)(BsB + (it * 32 + a_r0) * 128 + a_kc * 2) = r;
        }
        __syncthreads();
        #pragma unroll
        for (int kh = 0; kh < 2; ++kh) {
            const int kb = kh * 4 + (lane >> 4);
            bf16x8 af[4], bfr[4];
            #pragma unroll
            for (int m = 0; m < 4; ++m) {
                const int r = wr * 64 + m * 16 + (lane & 15);
                af[m] = *(const bf16x8*)(AsB + r * 128 + kb * 16);
            }
            #pragma unroll
            for (int n = 0; n < 4; ++n) {
                const int r = wc * 64 + n * 16 + (lane & 15);
                bfr[n] = *(const bf16x8*)(BsB + r * 128 + kb * 16);
            }
            #pragma unroll
            for (int m = 0; m < 4; ++m)
                #pragma unroll
                for (int n = 0; n < 4; ++n)
                    acc[m][n] = __builtin_amdgcn_mfma_f32_16x16x32_bf16(
                        af[m], bfr[n], acc[m][n], 0, 0, 0);
        }
    }
    const int fr = lane & 15, fq = (lane >> 4) * 4;
    #pragma unroll
    for (int m = 0; m < 4; ++m)
        #pragma unroll
        for (int n = 0; n < 4; ++n)
            #pragma unroll
            for (int j = 0; j < 4; ++j) {
                const int gr = row0 + wr * 64 + m * 16 + fq + j;
                const int gc = col0 + wc * 64 + n * 16 + fr;
                C[(size_t)gr * H + gc] = acc[m][n][j];
            }
}

// ---------------------------------------------------------------------------
// Host. d_in[2] is FP32 (npz upcast). ws: [0,134MB)=normed-x bf16,
// [134MB,268MB)=W bf16. Fallback if ws too small.
// ---------------------------------------------------------------------------
extern "C" void kernel_launch(void* const* d_in, const int* in_sizes, int n_in,
                              void* d_out, int out_size, void* d_ws, size_t ws_size,
                              hipStream_t stream) {
    (void)in_sizes; (void)n_in; (void)out_size;
    const float* x  = (const float*)d_in[0];
    const float* nw = (const float*)d_in[1];
    const float* wf = (const float*)d_in[2];
    float* out = (float*)d_out;

    const size_t xe_bytes = (size_t)NROWS * H * 2;
    const size_t we_bytes = (size_t)NEXP * H * H * 2;

    if (ws_size >= xe_bytes + we_bytes) {
        __bf16* ws_x = (__bf16*)d_ws;
        __bf16* ws_w = (__bf16*)((char*)d_ws + xe_bytes);
        norm_convert<<<2048, 256, 0, stream>>>(x, nw, ws_x);
        w_convert<<<2048, 256, 0, stream>>>(wf, ws_w);
        gemm_bf16_gdb<<<1024, 512, 0, stream>>>(ws_x, ws_w, out);
    } else {
        dim3 grid(H / BN, 4096 / BM);
        for (int i = 0; i < NEXP; ++i) {
            fused_norm_gemm_f32w<<<grid, 256, 0, stream>>>(
                x + (size_t)i * 4096 * H, nw + (size_t)i * H,
                wf + (size_t)i * H * H, out + (size_t)i * 4096 * H);
        }
    }
}

// Round 21
// 645.319 us; speedup vs baseline: 9.4066x; 1.0290x over previous
//
#include <hip/hip_runtime.h>

// ============================================================================
// ROUND 21: KEEPER. r18 GEMM verbatim (measured best: GEMM 516-518 us,
// MfmaUtil 48.6, 0 bank conflicts, total 637.8 us) + the two convert kernels
// fused into ONE grid-stride dispatch (same bytes, one less launch).
// Ledger: r14 521 | r15 622 | r16 575 | r17 641 | r18 516 | r20 558 -> r18
// structure is the verified local optimum (T1+T2+T3+T4+T5 all engaged).
// ============================================================================

#define H     4096
#define NROWS 16384
#define NEXP  4
#define NT    64          // K-tiles of 64

typedef __attribute__((ext_vector_type(8))) __bf16 bf16x8;
typedef __attribute__((ext_vector_type(4))) float  f32x4;

#define BAR()    asm volatile("s_barrier" ::: "memory")
#define VMCNT0() asm volatile("s_waitcnt vmcnt(0)" ::: "memory")
#define VMCNT4() asm volatile("s_waitcnt vmcnt(4)" ::: "memory")

__device__ __forceinline__ void gload16(const char* g, char* l) {
    __builtin_amdgcn_global_load_lds(
        (const __attribute__((address_space(1))) void*)g,
        (__attribute__((address_space(3))) void*)l, 16, 0, 0);
}

// ---------------------------------------------------------------------------
// Fused convert kernel (memory-bound, ~786 MB total, HBM roofline ~125 us).
// Range [0, nx8): normed-x -> bf16.  Range [nx8, 2*nx8): W fp32 -> bf16.
// ---------------------------------------------------------------------------
__global__ __launch_bounds__(256) void fused_convert(
    const float* __restrict__ x, const float* __restrict__ nw,
    const float* __restrict__ wf,
    __bf16* __restrict__ ox, __bf16* __restrict__ ow) {
    const size_t nx8  = (size_t)NROWS * H / 8;   // 8,388,608
    const size_t ntot = nx8 * 2;
    for (size_t i = (size_t)blockIdx.x * 256 + threadIdx.x; i < ntot;
         i += (size_t)gridDim.x * 256) {
        if (i < nx8) {
            const size_t base = i * 8;
            const int e = (int)(base >> 24);
            const int k = (int)(base & (size_t)(H - 1));
            const float4 v0 = *(const float4*)(x + base);
            const float4 v1 = *(const float4*)(x + base + 4);
            const float4 w0 = *(const float4*)(nw + (size_t)e * H + k);
            const float4 w1 = *(const float4*)(nw + (size_t)e * H + k + 4);
            bf16x8 r;
            r[0] = (__bf16)(v0.x * (w0.x + 1.0f));
            r[1] = (__bf16)(v0.y * (w0.y + 1.0f));
            r[2] = (__bf16)(v0.z * (w0.z + 1.0f));
            r[3] = (__bf16)(v0.w * (w0.w + 1.0f));
            r[4] = (__bf16)(v1.x * (w1.x + 1.0f));
            r[5] = (__bf16)(v1.y * (w1.y + 1.0f));
            r[6] = (__bf16)(v1.z * (w1.z + 1.0f));
            r[7] = (__bf16)(v1.w * (w1.w + 1.0f));
            *(bf16x8*)(ox + base) = r;
        } else {
            const size_t base = (i - nx8) * 8;
            const float4 v0 = *(const float4*)(wf + base);
            const float4 v1 = *(const float4*)(wf + base + 4);
            bf16x8 r;
            r[0] = (__bf16)v0.x; r[1] = (__bf16)v0.y;
            r[2] = (__bf16)v0.z; r[3] = (__bf16)v0.w;
            r[4] = (__bf16)v1.x; r[5] = (__bf16)v1.y;
            r[6] = (__bf16)v1.z; r[7] = (__bf16)v1.w;
            *(bf16x8*)(ow + base) = r;
        }
    }
}

// ---------------------------------------------------------------------------
// 8-phase 256^2 GEMM (r18 verbatim). 512 threads = 8 waves (2Mx4N).
// Per phase: ds_reads first, then 1 granule staged, BAR, setprio+16 MFMA,
// vmcnt(4) at P2/P4 only (counted, never 0 in-loop).
// ---------------------------------------------------------------------------
__global__ __launch_bounds__(512, 2) void gemm_bf16_8ph(
    const __bf16* __restrict__ A,    // (NROWS, H) bf16
    const __bf16* __restrict__ Wb,   // (NEXP, H, H) bf16
    float* __restrict__ C) {         // (NROWS, H) fp32
    __shared__ __align__(16) char lds[131072];

    const int tid  = threadIdx.x;
    const int lane = tid & 63;
    const int w    = tid >> 6;    // 0..7
    const int wr   = w >> 2;      // 0..1: rows wr*128..+127
    const int wc   = w & 3;       // 0..3: cols wc*64..+63

    // T1: bijective XCD swizzle (1024 blocks, 1024%8==0).
    const int bid = blockIdx.x;
    const int swz = (bid & 7) * 128 + (bid >> 3);
    const int bx  = swz & 15;
    const int by  = swz >> 4;
    const int e   = by >> 4;
    const int row0 = by * 256;
    const int col0 = bx * 256;

    const char* Ab = (const char*)A;
    const char* Bb = (const char*)(Wb + (size_t)e * H * H);

    const int    srow  = tid >> 2;
    const int    sslot = (((tid & 3) ^ ((tid >> 3) & 3)) << 4);
    const size_t a_g0  = ((size_t)(row0 + srow) * H) * 2 + sslot;
    const size_t a_g1  = a_g0 + (size_t)128 * H * 2;
    const size_t b_g0  = ((size_t)(col0 + srow) * H) * 2 + sslot;
    const size_t b_g1  = b_g0 + (size_t)128 * H * 2;
    const int    lds_t = tid * 16;

    const int l15   = lane & 15;
    const int slog  = lane >> 4;
    const int pslot = ((slog ^ ((l15 >> 1) & 3)) << 4);

    f32x4 acc[8][4] = {};

#define STAGE(base, koff, g0, g1, ldst)                       \
    do {                                                      \
        gload16(base + g0 + (koff), (ldst) + lds_t);          \
        gload16(base + g1 + (koff), (ldst) + 8192 + lds_t);   \
    } while (0)
#define LDF(dst, gran, rowe) \
    dst = *(const bf16x8*)((gran) + (rowe) * 64 + pslot)

    // ---- prologue: stage all 4 granules of tile 0, drain, barrier ----
    {
        char* A0 = lds;
        char* B0 = lds + 32768;
        STAGE(Ab, 0,  a_g0, a_g1, A0);
        STAGE(Bb, 0,  b_g0, b_g1, B0);
        STAGE(Ab, 64, a_g0, a_g1, A0 + 16384);
        STAGE(Bb, 64, b_g0, b_g1, B0 + 16384);
        VMCNT0();
        BAR();
    }

    for (int t = 0; t < NT; ++t) {
        char* curA = lds + (t & 1) * 65536;
        char* curB = curA + 32768;
        char* nxtA = lds + ((t & 1) ^ 1) * 65536;
        char* nxtB = nxtA + 32768;
        const size_t kn0 = (size_t)(t + 1) * 128;
        const size_t kn1 = kn0 + 64;
        const bool   st  = (t + 1 < NT);

        bf16x8 a[4], b0[4], b1[4];

        // ---- P1: read B-kh0, A-kh0 rows 0-63 | stage A-kh0(t+1) | MFMA ----
        #pragma unroll
        for (int n = 0; n < 4; ++n) LDF(b0[n], curB, wc * 64 + n * 16 + l15);
        #pragma unroll
        for (int m = 0; m < 4; ++m) LDF(a[m], curA, wr * 128 + m * 16 + l15);
        if (st) STAGE(Ab, kn0, a_g0, a_g1, nxtA);
        BAR();
        __builtin_amdgcn_s_setprio(1);
        #pragma unroll
        for (int m = 0; m < 4; ++m)
            #pragma unroll
            for (int n = 0; n < 4; ++n)
                acc[m][n] = __builtin_amdgcn_mfma_f32_16x16x32_bf16(
                    a[m], b0[n], acc[m][n], 0, 0, 0);
        __builtin_amdgcn_s_setprio(0);
        BAR();

        // ---- P2: read A-kh0 rows 64-127 | stage B-kh0(t+1) | MFMA | vm ----
        #pragma unroll
        for (int m = 0; m < 4; ++m) LDF(a[m], curA, wr * 128 + 64 + m * 16 + l15);
        if (st) STAGE(Bb, kn0, b_g0, b_g1, nxtB);
        BAR();
        __builtin_amdgcn_s_setprio(1);
        #pragma unroll
        for (int m = 0; m < 4; ++m)
            #pragma unroll
            for (int n = 0; n < 4; ++n)
                acc[4 + m][n] = __builtin_amdgcn_mfma_f32_16x16x32_bf16(
                    a[m], b0[n], acc[4 + m][n], 0, 0, 0);
        __builtin_amdgcn_s_setprio(0);
        if (st) VMCNT4(); else VMCNT0();   // A-kh1(t), B-kh1(t) resident
        BAR();

        // ---- P3: read B-kh1, A-kh1 rows 0-63 | stage A-kh1(t+1) | MFMA ----
        #pragma unroll
        for (int n = 0; n < 4; ++n) LDF(b1[n], curB + 16384, wc * 64 + n * 16 + l15);
        #pragma unroll
        for (int m = 0; m < 4; ++m) LDF(a[m], curA + 16384, wr * 128 + m * 16 + l15);
        if (st) STAGE(Ab, kn1, a_g0, a_g1, nxtA + 16384);
        BAR();
        __builtin_amdgcn_s_setprio(1);
        #pragma unroll
        for (int m = 0; m < 4; ++m)
            #pragma unroll
            for (int n = 0; n < 4; ++n)
                acc[m][n] = __builtin_amdgcn_mfma_f32_16x16x32_bf16(
                    a[m], b1[n], acc[m][n], 0, 0, 0);
        __builtin_amdgcn_s_setprio(0);
        BAR();

        // ---- P4: read A-kh1 rows 64-127 | stage B-kh1(t+1) | MFMA | vm ----
        #pragma unroll
        for (int m = 0; m < 4; ++m) LDF(a[m], curA + 16384, wr * 128 + 64 + m * 16 + l15);
        if (st) STAGE(Bb, kn1, b_g0, b_g1, nxtB + 16384);
        BAR();
        __builtin_amdgcn_s_setprio(1);
        #pragma unroll
        for (int m = 0; m < 4; ++m)
            #pragma unroll
            for (int n = 0; n < 4; ++n)
                acc[4 + m][n] = __builtin_amdgcn_mfma_f32_16x16x32_bf16(
                    a[m], b1[n], acc[4 + m][n], 0, 0, 0);
        __builtin_amdgcn_s_setprio(0);
        if (st) VMCNT4();                  // A-kh0(t+1), B-kh0(t+1) resident
        BAR();
    }

    // Epilogue: C/D layout col = lane&15, row = (lane>>4)*4 + j  [m89].
    const int fq = slog * 4;
    #pragma unroll
    for (int m8 = 0; m8 < 8; ++m8) {
        #pragma unroll
        for (int n = 0; n < 4; ++n) {
            #pragma unroll
            for (int j = 0; j < 4; ++j) {
                const int gr = row0 + wr * 128 + m8 * 16 + fq + j;
                const int gc = col0 + wc * 64 + n * 16 + l15;
                C[(size_t)gr * H + gc] = acc[m8][n][j];
            }
        }
    }
#undef STAGE
#undef LDF
}

// ---------------------------------------------------------------------------
// FALLBACK (ws too small): round-12 fused kernel (verified passing, 430 TF).
// ---------------------------------------------------------------------------
#define BM 128
#define BN 128
#define BK 64
__global__ __launch_bounds__(256, 2) void fused_norm_gemm_f32w(
    const float* __restrict__ X, const float* __restrict__ NW,
    const float* __restrict__ Wf, float* __restrict__ C) {
    __shared__ __align__(16) __bf16 As[BM * BK];
    __shared__ __align__(16) __bf16 Bs[BN * BK];
    const int tid = threadIdx.x, lane = tid & 63, w = tid >> 6;
    const int wr = w >> 1, wc = w & 1;
    const int row0 = blockIdx.y * BM, col0 = blockIdx.x * BN;
    f32x4 acc[4][4] = {};
    const int a_kc = (tid & 7) * 8, a_r0 = tid >> 3;
    char* AsB = (char*)As; char* BsB = (char*)Bs;
    for (int kt = 0; kt < H; kt += BK) {
        __syncthreads();
        float4 xv[4][2], bv[4][2];
        #pragma unroll
        for (int it = 0; it < 4; ++it) {
            const float* xp = X + (size_t)(row0 + it * 32 + a_r0) * H + kt + a_kc;
            xv[it][0] = *(const float4*)xp; xv[it][1] = *(const float4*)(xp + 4);
        }
        #pragma unroll
        for (int it = 0; it < 4; ++it) {
            const float* bp = Wf + (size_t)(col0 + it * 32 + a_r0) * H + kt + a_kc;
            bv[it][0] = *(const float4*)bp; bv[it][1] = *(const float4*)(bp + 4);
        }
        float4 w0 = *(const float4*)(NW + kt + a_kc);
        float4 w1 = *(const float4*)(NW + kt + a_kc + 4);
        w0.x += 1.0f; w0.y += 1.0f; w0.z += 1.0f; w0.w += 1.0f;
        w1.x += 1.0f; w1.y += 1.0f; w1.z += 1.0f; w1.w += 1.0f;
        #pragma unroll
        for (int it = 0; it < 4; ++it) {
            bf16x8 r;
            r[0] = (__bf16)(xv[it][0].x * w0.x); r[1] = (__bf16)(xv[it][0].y * w0.y);
            r[2] = (__bf16)(xv[it][0].z * w0.z); r[3] = (__bf16)(xv[it][0].w * w0.w);
            r[4] = (__bf16)(xv[it][1].x * w1.x); r[5] = (__bf16)(xv[it][1].y * w1.y);
            r[6] = (__bf16)(xv[it][1].z * w1.z); r[7] = (__bf16)(xv[it][1].w * w1.w);
            *(bf16x8*)(AsB + (it * 32 + a_r0) * 128 + a_kc * 2) = r;
        }
        #pragma unroll
        for (int it = 0; it < 4; ++it) {
            bf16x8 r;
            r[0] = (__bf16)bv[it][0].x; r[1] = (__bf16)bv[it][0].y;
            r[2] = (__bf16)bv[it][0].z; r[3] = (__bf16)bv[it][0].w;
            r[4] = (__bf16)bv[it][1].x; r[5] = (__bf16)bv[it][1].y;
            r[6] = (__bf16)bv[it][1].z; r[7] = (__bf16)bv[it][1].w;
            *(bf16x8*)(BsB + (it * 32 + a_r0) * 128 + a_kc * 2) = r;
        }
        __syncthreads();
        #pragma unroll
        for (int kh = 0; kh < 2; ++kh) {
            const int kb = kh * 4 + (lane >> 4);
            bf16x8 af[4], bfr[4];
            #pragma unroll
            for (int m = 0; m < 4; ++m) {
                const int r = wr * 64 + m * 16 + (lane & 15);
                af[m] = *(const bf16x8*)(AsB + r * 128 + kb * 16);
            }
            #pragma unroll
            for (int n = 0; n < 4; ++n) {
                const int r = wc * 64 + n * 16 + (lane & 15);
                bfr[n] = *(const bf16x8*)(BsB + r * 128 + kb * 16);
            }
            #pragma unroll
            for (int m = 0; m < 4; ++m)
                #pragma unroll
                for (int n = 0; n < 4; ++n)
                    acc[m][n] = __builtin_amdgcn_mfma_f32_16x16x32_bf16(
                        af[m], bfr[n], acc[m][n], 0, 0, 0);
        }
    }
    const int fr = lane & 15, fq = (lane >> 4) * 4;
    #pragma unroll
    for (int m = 0; m < 4; ++m)
        #pragma unroll
        for (int n = 0; n < 4; ++n)
            #pragma unroll
            for (int j = 0; j < 4; ++j) {
                const int gr = row0 + wr * 64 + m * 16 + fq + j;
                const int gc = col0 + wc * 64 + n * 16 + fr;
                C[(size_t)gr * H + gc] = acc[m][n][j];
            }
}

// ---------------------------------------------------------------------------
// Host. d_in[2] is FP32 (npz upcast, bf16-grid values). ws: [0,134MB) =
// normed-x bf16, [134MB,268MB) = W bf16. Fallback if ws too small.
// ---------------------------------------------------------------------------
extern "C" void kernel_launch(void* const* d_in, const int* in_sizes, int n_in,
                              void* d_out, int out_size, void* d_ws, size_t ws_size,
                              hipStream_t stream) {
    (void)in_sizes; (void)n_in; (void)out_size;
    const float* x  = (const float*)d_in[0];
    const float* nw = (const float*)d_in[1];
    const float* wf = (const float*)d_in[2];
    float* out = (float*)d_out;

    const size_t xe_bytes = (size_t)NROWS * H * 2;
    const size_t we_bytes = (size_t)NEXP * H * H * 2;

    if (ws_size >= xe_bytes + we_bytes) {
        __bf16* ws_x = (__bf16*)d_ws;
        __bf16* ws_w = (__bf16*)((char*)d_ws + xe_bytes);
        fused_convert<<<2048, 256, 0, stream>>>(x, nw, wf, ws_x, ws_w);
        gemm_bf16_8ph<<<1024, 512, 0, stream>>>(ws_x, ws_w, out);
    } else {
        dim3 grid(H / BN, 4096 / BM);
        for (int i = 0; i < NEXP; ++i) {
            fused_norm_gemm_f32w<<<grid, 256, 0, stream>>>(
                x + (size_t)i * 4096 * H, nw + (size_t)i * H,
                wf + (size_t)i * H * H, out + (size_t)i * 4096 * H);
        }
    }
}

// Round 22
// 641.386 us; speedup vs baseline: 9.4642x; 1.0061x over previous
//
#include <hip/hip_runtime.h>

// ============================================================================
// FINAL (lock-in): r18 exact — best measured total 637.8 us.
//   1) norm_convert + w_convert: HBM-roofline bf16 materialization (~121 us)
//   2) gemm_bf16_8ph: 256^2 tile, 8 waves (2Mx4N), 16x16x32 MFMA,
//      8-phase schedule (ds_reads first, 1 granule staged/phase, counted
//      vmcnt(4) at P2/P4 — never 0 in-loop), XOR swizzle (0 bank conflicts),
//      bijective XCD swizzle, setprio around MFMA clusters.
// Ledger (GEMM us/MfmaUtil): r13 m97=712/34.5 | r14=521/47.7 | r15=622/38 |
// r16=575/44 | r17=641/36 | r18=516/48.6 (BEST) | r19=spill | r20=558/44 |
// r21 fused-convert=noise. All departures from r18 regressed -> converged.
// ============================================================================

#define H     4096
#define NROWS 16384
#define NEXP  4
#define NT    64          // K-tiles of 64

typedef __attribute__((ext_vector_type(8))) __bf16 bf16x8;
typedef __attribute__((ext_vector_type(4))) float  f32x4;

#define BAR()    asm volatile("s_barrier" ::: "memory")
#define VMCNT0() asm volatile("s_waitcnt vmcnt(0)" ::: "memory")
#define VMCNT4() asm volatile("s_waitcnt vmcnt(4)" ::: "memory")

__device__ __forceinline__ void gload16(const char* g, char* l) {
    __builtin_amdgcn_global_load_lds(
        (const __attribute__((address_space(1))) void*)g,
        (__attribute__((address_space(3))) void*)l, 16, 0, 0);
}

// ---------------------------------------------------------------------------
// Convert kernels (memory-bound; at HBM roofline, ~121 us total).
// ---------------------------------------------------------------------------
__global__ __launch_bounds__(256) void norm_convert(
    const float* __restrict__ x, const float* __restrict__ nw,
    __bf16* __restrict__ out) {
    const size_t nthread8 = (size_t)NROWS * H / 8;
    for (size_t i = (size_t)blockIdx.x * 256 + threadIdx.x; i < nthread8;
         i += (size_t)gridDim.x * 256) {
        const size_t base = i * 8;
        const int e = (int)(base >> 24);
        const int k = (int)(base & (size_t)(H - 1));
        const float4 v0 = *(const float4*)(x + base);
        const float4 v1 = *(const float4*)(x + base + 4);
        const float4 w0 = *(const float4*)(nw + (size_t)e * H + k);
        const float4 w1 = *(const float4*)(nw + (size_t)e * H + k + 4);
        bf16x8 r;
        r[0] = (__bf16)(v0.x * (w0.x + 1.0f));
        r[1] = (__bf16)(v0.y * (w0.y + 1.0f));
        r[2] = (__bf16)(v0.z * (w0.z + 1.0f));
        r[3] = (__bf16)(v0.w * (w0.w + 1.0f));
        r[4] = (__bf16)(v1.x * (w1.x + 1.0f));
        r[5] = (__bf16)(v1.y * (w1.y + 1.0f));
        r[6] = (__bf16)(v1.z * (w1.z + 1.0f));
        r[7] = (__bf16)(v1.w * (w1.w + 1.0f));
        *(bf16x8*)(out + base) = r;
    }
}

__global__ __launch_bounds__(256) void w_convert(
    const float* __restrict__ wf, __bf16* __restrict__ out) {
    const size_t nthread8 = (size_t)NEXP * H * H / 8;
    for (size_t i = (size_t)blockIdx.x * 256 + threadIdx.x; i < nthread8;
         i += (size_t)gridDim.x * 256) {
        const size_t base = i * 8;
        const float4 v0 = *(const float4*)(wf + base);
        const float4 v1 = *(const float4*)(wf + base + 4);
        bf16x8 r;
        r[0] = (__bf16)v0.x; r[1] = (__bf16)v0.y;
        r[2] = (__bf16)v0.z; r[3] = (__bf16)v0.w;
        r[4] = (__bf16)v1.x; r[5] = (__bf16)v1.y;
        r[6] = (__bf16)v1.z; r[7] = (__bf16)v1.w;
        *(bf16x8*)(out + base) = r;
    }
}

// ---------------------------------------------------------------------------
// 8-phase 256^2 GEMM. 512 threads = 8 waves (2 row-halves x 4 col-quarters).
// ---------------------------------------------------------------------------
__global__ __launch_bounds__(512, 2) void gemm_bf16_8ph(
    const __bf16* __restrict__ A,    // (NROWS, H) bf16
    const __bf16* __restrict__ Wb,   // (NEXP, H, H) bf16
    float* __restrict__ C) {         // (NROWS, H) fp32
    __shared__ __align__(16) char lds[131072];

    const int tid  = threadIdx.x;
    const int lane = tid & 63;
    const int w    = tid >> 6;    // 0..7
    const int wr   = w >> 2;      // 0..1: rows wr*128..+127
    const int wc   = w & 3;       // 0..3: cols wc*64..+63

    // T1: bijective XCD swizzle (1024 blocks, 1024%8==0).
    const int bid = blockIdx.x;
    const int swz = (bid & 7) * 128 + (bid >> 3);
    const int bx  = swz & 15;
    const int by  = swz >> 4;
    const int e   = by >> 4;
    const int row0 = by * 256;
    const int col0 = bx * 256;

    const char* Ab = (const char*)A;
    const char* Bb = (const char*)(Wb + (size_t)e * H * H);

    const int    srow  = tid >> 2;
    const int    sslot = (((tid & 3) ^ ((tid >> 3) & 3)) << 4);
    const size_t a_g0  = ((size_t)(row0 + srow) * H) * 2 + sslot;
    const size_t a_g1  = a_g0 + (size_t)128 * H * 2;
    const size_t b_g0  = ((size_t)(col0 + srow) * H) * 2 + sslot;
    const size_t b_g1  = b_g0 + (size_t)128 * H * 2;
    const int    lds_t = tid * 16;

    const int l15   = lane & 15;
    const int slog  = lane >> 4;
    const int pslot = ((slog ^ ((l15 >> 1) & 3)) << 4);

    f32x4 acc[8][4] = {};

#define STAGE(base, koff, g0, g1, ldst)                       \
    do {                                                      \
        gload16(base + g0 + (koff), (ldst) + lds_t);          \
        gload16(base + g1 + (koff), (ldst) + 8192 + lds_t);   \
    } while (0)
#define LDF(dst, gran, rowe) \
    dst = *(const bf16x8*)((gran) + (rowe) * 64 + pslot)

    // ---- prologue: stage all 4 granules of tile 0, drain, barrier ----
    {
        char* A0 = lds;
        char* B0 = lds + 32768;
        STAGE(Ab, 0,  a_g0, a_g1, A0);
        STAGE(Bb, 0,  b_g0, b_g1, B0);
        STAGE(Ab, 64, a_g0, a_g1, A0 + 16384);
        STAGE(Bb, 64, b_g0, b_g1, B0 + 16384);
        VMCNT0();
        BAR();
    }

    for (int t = 0; t < NT; ++t) {
        char* curA = lds + (t & 1) * 65536;
        char* curB = curA + 32768;
        char* nxtA = lds + ((t & 1) ^ 1) * 65536;
        char* nxtB = nxtA + 32768;
        const size_t kn0 = (size_t)(t + 1) * 128;
        const size_t kn1 = kn0 + 64;
        const bool   st  = (t + 1 < NT);

        bf16x8 a[4], b0[4], b1[4];

        // ---- P1: read B-kh0, A-kh0 rows 0-63 | stage A-kh0(t+1) | MFMA ----
        #pragma unroll
        for (int n = 0; n < 4; ++n) LDF(b0[n], curB, wc * 64 + n * 16 + l15);
        #pragma unroll
        for (int m = 0; m < 4; ++m) LDF(a[m], curA, wr * 128 + m * 16 + l15);
        if (st) STAGE(Ab, kn0, a_g0, a_g1, nxtA);
        BAR();
        __builtin_amdgcn_s_setprio(1);
        #pragma unroll
        for (int m = 0; m < 4; ++m)
            #pragma unroll
            for (int n = 0; n < 4; ++n)
                acc[m][n] = __builtin_amdgcn_mfma_f32_16x16x32_bf16(
                    a[m], b0[n], acc[m][n], 0, 0, 0);
        __builtin_amdgcn_s_setprio(0);
        BAR();

        // ---- P2: read A-kh0 rows 64-127 | stage B-kh0(t+1) | MFMA | vm ----
        #pragma unroll
        for (int m = 0; m < 4; ++m) LDF(a[m], curA, wr * 128 + 64 + m * 16 + l15);
        if (st) STAGE(Bb, kn0, b_g0, b_g1, nxtB);
        BAR();
        __builtin_amdgcn_s_setprio(1);
        #pragma unroll
        for (int m = 0; m < 4; ++m)
            #pragma unroll
            for (int n = 0; n < 4; ++n)
                acc[4 + m][n] = __builtin_amdgcn_mfma_f32_16x16x32_bf16(
                    a[m], b0[n], acc[4 + m][n], 0, 0, 0);
        __builtin_amdgcn_s_setprio(0);
        if (st) VMCNT4(); else VMCNT0();   // A-kh1(t), B-kh1(t) resident
        BAR();

        // ---- P3: read B-kh1, A-kh1 rows 0-63 | stage A-kh1(t+1) | MFMA ----
        #pragma unroll
        for (int n = 0; n < 4; ++n) LDF(b1[n], curB + 16384, wc * 64 + n * 16 + l15);
        #pragma unroll
        for (int m = 0; m < 4; ++m) LDF(a[m], curA + 16384, wr * 128 + m * 16 + l15);
        if (st) STAGE(Ab, kn1, a_g0, a_g1, nxtA + 16384);
        BAR();
        __builtin_amdgcn_s_setprio(1);
        #pragma unroll
        for (int m = 0; m < 4; ++m)
            #pragma unroll
            for (int n = 0; n < 4; ++n)
                acc[m][n] = __builtin_amdgcn_mfma_f32_16x16x32_bf16(
                    a[m], b1[n], acc[m][n], 0, 0, 0);
        __builtin_amdgcn_s_setprio(0);
        BAR();

        // ---- P4: read A-kh1 rows 64-127 | stage B-kh1(t+1) | MFMA | vm ----
        #pragma unroll
        for (int m = 0; m < 4; ++m) LDF(a[m], curA + 16384, wr * 128 + 64 + m * 16 + l15);
        if (st) STAGE(Bb, kn1, b_g0, b_g1, nxtB + 16384);
        BAR();
        __builtin_amdgcn_s_setprio(1);
        #pragma unroll
        for (int m = 0; m < 4; ++m)
            #pragma unroll
            for (int n = 0; n < 4; ++n)
                acc[4 + m][n] = __builtin_amdgcn_mfma_f32_16x16x32_bf16(
                    a[m], b1[n], acc[4 + m][n], 0, 0, 0);
        __builtin_amdgcn_s_setprio(0);
        if (st) VMCNT4();                  // A-kh0(t+1), B-kh0(t+1) resident
        BAR();
    }

    // Epilogue: C/D layout col = lane&15, row = (lane>>4)*4 + j  [m89].
    const int fq = slog * 4;
    #pragma unroll
    for (int m8 = 0; m8 < 8; ++m8) {
        #pragma unroll
        for (int n = 0; n < 4; ++n) {
            #pragma unroll
            for (int j = 0; j < 4; ++j) {
                const int gr = row0 + wr * 128 + m8 * 16 + fq + j;
                const int gc = col0 + wc * 64 + n * 16 + l15;
                C[(size_t)gr * H + gc] = acc[m8][n][j];
            }
        }
    }
#undef STAGE
#undef LDF
}

// ---------------------------------------------------------------------------
// FALLBACK (ws too small): round-12 fused kernel (verified passing, 430 TF).
// ---------------------------------------------------------------------------
#define BM 128
#define BN 128
#define BK 64
__global__ __launch_bounds__(256, 2) void fused_norm_gemm_f32w(
    const float* __restrict__ X, const float* __restrict__ NW,
    const float* __restrict__ Wf, float* __restrict__ C) {
    __shared__ __align__(16) __bf16 As[BM * BK];
    __shared__ __align__(16) __bf16 Bs[BN * BK];
    const int tid = threadIdx.x, lane = tid & 63, w = tid >> 6;
    const int wr = w >> 1, wc = w & 1;
    const int row0 = blockIdx.y * BM, col0 = blockIdx.x * BN;
    f32x4 acc[4][4] = {};
    const int a_kc = (tid & 7) * 8, a_r0 = tid >> 3;
    char* AsB = (char*)As; char* BsB = (char*)Bs;
    for (int kt = 0; kt < H; kt += BK) {
        __syncthreads();
        float4 xv[4][2], bv[4][2];
        #pragma unroll
        for (int it = 0; it < 4; ++it) {
            const float* xp = X + (size_t)(row0 + it * 32 + a_r0) * H + kt + a_kc;
            xv[it][0] = *(const float4*)xp; xv[it][1] = *(const float4*)(xp + 4);
        }
        #pragma unroll
        for (int it = 0; it < 4; ++it) {
            const float* bp = Wf + (size_t)(col0 + it * 32 + a_r0) * H + kt + a_kc;
            bv[it][0] = *(const float4*)bp; bv[it][1] = *(const float4*)(bp + 4);
        }
        float4 w0 = *(const float4*)(NW + kt + a_kc);
        float4 w1 = *(const float4*)(NW + kt + a_kc + 4);
        w0.x += 1.0f; w0.y += 1.0f; w0.z += 1.0f; w0.w += 1.0f;
        w1.x += 1.0f; w1.y += 1.0f; w1.z += 1.0f; w1.w += 1.0f;
        #pragma unroll
        for (int it = 0; it < 4; ++it) {
            bf16x8 r;
            r[0] = (__bf16)(xv[it][0].x * w0.x); r[1] = (__bf16)(xv[it][0].y * w0.y);
            r[2] = (__bf16)(xv[it][0].z * w0.z); r[3] = (__bf16)(xv[it][0].w * w0.w);
            r[4] = (__bf16)(xv[it][1].x * w1.x); r[5] = (__bf16)(xv[it][1].y * w1.y);
            r[6] = (__bf16)(xv[it][1].z * w1.z); r[7] = (__bf16)(xv[it][1].w * w1.w);
            *(bf16x8*)(AsB + (it * 32 + a_r0) * 128 + a_kc * 2) = r;
        }
        #pragma unroll
        for (int it = 0; it < 4; ++it) {
            bf16x8 r;
            r[0] = (__bf16)bv[it][0].x; r[1] = (__bf16)bv[it][0].y;
            r[2] = (__bf16)bv[it][0].z; r[3] = (__bf16)bv[it][0].w;
            r[4] = (__bf16)bv[it][1].x; r[5] = (__bf16)bv[it][1].y;
            r[6] = (__bf16)bv[it][1].z; r[7] = (__bf16)bv[it][1].w;
            *(bf16x8*)(BsB + (it * 32 + a_r0) * 128 + a_kc * 2) = r;
        }
        __syncthreads();
        #pragma unroll
        for (int kh = 0; kh < 2; ++kh) {
            const int kb = kh * 4 + (lane >> 4);
            bf16x8 af[4], bfr[4];
            #pragma unroll
            for (int m = 0; m < 4; ++m) {
                const int r = wr * 64 + m * 16 + (lane & 15);
                af[m] = *(const bf16x8*)(AsB + r * 128 + kb * 16);
            }
            #pragma unroll
            for (int n = 0; n < 4; ++n) {
                const int r = wc * 64 + n * 16 + (lane & 15);
                bfr[n] = *(const bf16x8*)(BsB + r * 128 + kb * 16);
            }
            #pragma unroll
            for (int m = 0; m < 4; ++m)
                #pragma unroll
                for (int n = 0; n < 4; ++n)
                    acc[m][n] = __builtin_amdgcn_mfma_f32_16x16x32_bf16(
                        af[m], bfr[n], acc[m][n], 0, 0, 0);
        }
    }
    const int fr = lane & 15, fq = (lane >> 4) * 4;
    #pragma unroll
    for (int m = 0; m < 4; ++m)
        #pragma unroll
        for (int n = 0; n < 4; ++n)
            #pragma unroll
            for (int j = 0; j < 4; ++j) {
                const int gr = row0 + wr * 64 + m * 16 + fq + j;
                const int gc = col0 + wc * 64 + n * 16 + fr;
                C[(size_t)gr * H + gc] = acc[m][n][j];
            }
}

// ---------------------------------------------------------------------------
// Host. d_in[2] is FP32 (npz upcast, bf16-grid values). ws: [0,134MB) =
// normed-x bf16, [134MB,268MB) = W bf16. Fallback if ws too small.
// ---------------------------------------------------------------------------
extern "C" void kernel_launch(void* const* d_in, const int* in_sizes, int n_in,
                              void* d_out, int out_size, void* d_ws, size_t ws_size,
                              hipStream_t stream) {
    (void)in_sizes; (void)n_in; (void)out_size;
    const float* x  = (const float*)d_in[0];
    const float* nw = (const float*)d_in[1];
    const float* wf = (const float*)d_in[2];
    float* out = (float*)d_out;

    const size_t xe_bytes = (size_t)NROWS * H * 2;
    const size_t we_bytes = (size_t)NEXP * H * H * 2;

    if (ws_size >= xe_bytes + we_bytes) {
        __bf16* ws_x = (__bf16*)d_ws;
        __bf16* ws_w = (__bf16*)((char*)d_ws + xe_bytes);
        norm_convert<<<2048, 256, 0, stream>>>(x, nw, ws_x);
        w_convert<<<2048, 256, 0, stream>>>(wf, ws_w);
        gemm_bf16_8ph<<<1024, 512, 0, stream>>>(ws_x, ws_w, out);
    } else {
        dim3 grid(H / BN, 4096 / BM);
        for (int i = 0; i < NEXP; ++i) {
            fused_norm_gemm_f32w<<<grid, 256, 0, stream>>>(
                x + (size_t)i * 4096 * H, nw + (size_t)i * H,
                wf + (size_t)i * H * H, out + (size_t)i * 4096 * H);
        }
    }
}